// Round 1
// baseline (92.259 us; speedup 1.0000x reference)
//
#include <hip/hip_runtime.h>
#include <math.h>

#define FFT_LEN   1024
#define STEP      256
#define NFRAMES   8192
#define OUT_LEN   (STEP * (NFRAMES - 1) + FFT_LEN)   // 2097920
#define NVEC      (OUT_LEN / 4)                      // 524480 float4 outputs

__global__ __launch_bounds__(256) void istft_ola_kernel(
    const float* __restrict__ Sr,
    const float* __restrict__ Si,
    float* __restrict__ out)
{
    // Per-bin folded tables: A = (c - s) * w / n, B = (c + s) * w / n, W = w
    __shared__ float As[FFT_LEN];
    __shared__ float Bs[FFT_LEN];
    __shared__ float Ws[FFT_LEN];

    const float inv_n  = 1.0f / 1024.0f;
    const float two_pi = 6.283185307179586f;

    for (int j = (int)threadIdx.x; j < FFT_LEN; j += 256) {
        float theta = two_pi * (float)j * inv_n;
        float s, c;
        sincosf(theta, &s, &c);
        float w = 0.5f - 0.5f * c;          // periodic Hann (same theta: FRAME_LENGTH == FFT_LEN)
        As[j] = (c - s) * w * inv_n;
        Bs[j] = (c + s) * w * inv_n;
        Ws[j] = w;
    }
    __syncthreads();

    int v = (int)blockIdx.x * 256 + (int)threadIdx.x;
    if (v >= NVEC) return;

    int t0 = v << 2;              // first of 4 consecutive output samples
    int m0 = t0 & (STEP - 1);     // multiple of 4 (since 4 | 256)
    int q  = t0 >> 8;             // frame index of arm a=0

    float4 num = make_float4(0.f, 0.f, 0.f, 0.f);
    float4 den = make_float4(0.f, 0.f, 0.f, 0.f);

#pragma unroll
    for (int a = 0; a < 4; ++a) {
        int i = q - a;
        if ((unsigned)i < (unsigned)NFRAMES) {
            int j = m0 + a * STEP;                       // j in [0, 1024), 16B-aligned
            size_t base = (size_t)i * FFT_LEN + (size_t)j;
            const float4 R = *reinterpret_cast<const float4*>(Sr + base);
            const float4 I = *reinterpret_cast<const float4*>(Si + base);
            const float4 A = *reinterpret_cast<const float4*>(&As[j]);
            const float4 B = *reinterpret_cast<const float4*>(&Bs[j]);
            const float4 W = *reinterpret_cast<const float4*>(&Ws[j]);
            num.x = fmaf(R.x, A.x, fmaf(-I.x, B.x, num.x));
            num.y = fmaf(R.y, A.y, fmaf(-I.y, B.y, num.y));
            num.z = fmaf(R.z, A.z, fmaf(-I.z, B.z, num.z));
            num.w = fmaf(R.w, A.w, fmaf(-I.w, B.w, num.w));
            den.x += W.x; den.y += W.y; den.z += W.z; den.w += W.w;
        }
    }

    float4 o;
    o.x = num.x / fmaxf(den.x, 1e-8f);
    o.y = num.y / fmaxf(den.y, 1e-8f);
    o.z = num.z / fmaxf(den.z, 1e-8f);
    o.w = num.w / fmaxf(den.w, 1e-8f);
    *reinterpret_cast<float4*>(out + t0) = o;
}

extern "C" void kernel_launch(void* const* d_in, const int* in_sizes, int n_in,
                              void* d_out, int out_size, void* d_ws, size_t ws_size,
                              hipStream_t stream) {
    const float* Sr = (const float*)d_in[0];
    const float* Si = (const float*)d_in[1];
    float* out = (float*)d_out;
    (void)in_sizes; (void)n_in; (void)out_size; (void)d_ws; (void)ws_size;

    dim3 block(256);
    dim3 grid((NVEC + 255) / 256);   // 2049 blocks
    istft_ola_kernel<<<grid, block, 0, stream>>>(Sr, Si, out);
}

// Round 2
// 91.796 us; speedup vs baseline: 1.0050x; 1.0050x over previous
//
#include <hip/hip_runtime.h>
#include <math.h>

#define FFT_LEN   1024
#define STEP      256
#define NFRAMES   8192
#define OUT_LEN   (STEP * (NFRAMES - 1) + FFT_LEN)   // 2097920
#define NVEC      (OUT_LEN / 4)                      // 524480 float4 outputs
#define NBLK      1025
#define VSTRIDE   (NBLK * 256)                       // 262400; (VSTRIDE*4) % 256 == 0 -> same m0

__global__ __launch_bounds__(256) void istft_ola_kernel(
    const float* __restrict__ Sr,
    const float* __restrict__ Si,
    float* __restrict__ out)
{
    const float inv_n  = 1.0f / 1024.0f;
    const float two_pi = 6.283185307179586f;

    const int v0 = (int)blockIdx.x * 256 + (int)threadIdx.x;
    const int m0 = (v0 << 2) & (STEP - 1);           // same for both vecs this thread handles

    // Trig only for arm 0's four bins; arms 1..3 via quarter-turn identities.
    float c[4], s[4];
#pragma unroll
    for (int d = 0; d < 4; ++d) {
        float theta = two_pi * (float)(m0 + d) * inv_n;
        sincosf(theta, &s[d], &c[d]);
    }

    // A[a][d] = (c_a - s_a)*w_a/n ; B[a][d] = (c_a + s_a)*w_a/n ; w_a = 0.5 - 0.5*c_a
    // (c_a, s_a): a=0:(c,s)  a=1:(-s,c)  a=2:(-c,-s)  a=3:(s,-c)
    float A[4][4], B[4][4], W[4][4];
#pragma unroll
    for (int d = 0; d < 4; ++d) {
        const float cc = c[d], ss = s[d];
#pragma unroll
        for (int a = 0; a < 4; ++a) {
            const float ca = (a == 0) ? cc : (a == 1) ? -ss : (a == 2) ? -cc : ss;
            const float sa = (a == 0) ? ss : (a == 1) ? cc  : (a == 2) ? -ss : -cc;
            const float w  = 0.5f - 0.5f * ca;
            A[a][d] = (ca - sa) * w * inv_n;
            B[a][d] = (ca + sa) * w * inv_n;
            W[a][d] = w;
        }
    }

#pragma unroll
    for (int half = 0; half < 2; ++half) {
        const int v = v0 + half * VSTRIDE;
        if (half == 1 && v >= NVEC) break;

        const int t0 = v << 2;
        const int q  = t0 >> 8;                      // wave-uniform

        float num[4] = {0.f, 0.f, 0.f, 0.f};

        if (q >= 3 && q <= NFRAMES - 1) {
            // Interior: all 4 arms valid, Hann COLA sum == 2.0 exactly.
#pragma unroll
            for (int a = 0; a < 4; ++a) {
                const size_t base = (size_t)(q - a) * FFT_LEN + (size_t)(m0 + a * STEP);
                const float4 R = *reinterpret_cast<const float4*>(Sr + base);
                const float4 I = *reinterpret_cast<const float4*>(Si + base);
                num[0] = fmaf(R.x, A[a][0], fmaf(-I.x, B[a][0], num[0]));
                num[1] = fmaf(R.y, A[a][1], fmaf(-I.y, B[a][1], num[1]));
                num[2] = fmaf(R.z, A[a][2], fmaf(-I.z, B[a][2], num[2]));
                num[3] = fmaf(R.w, A[a][3], fmaf(-I.w, B[a][3], num[3]));
            }
            float4 o;
            o.x = num[0] * 0.5f;
            o.y = num[1] * 0.5f;
            o.z = num[2] * 0.5f;
            o.w = num[3] * 0.5f;
            *reinterpret_cast<float4*>(out + t0) = o;
        } else {
            // Edge: per-arm validity + true window-correction divide.
            float den[4] = {0.f, 0.f, 0.f, 0.f};
#pragma unroll
            for (int a = 0; a < 4; ++a) {
                const int i = q - a;
                if ((unsigned)i < (unsigned)NFRAMES) {
                    const size_t base = (size_t)i * FFT_LEN + (size_t)(m0 + a * STEP);
                    const float4 R = *reinterpret_cast<const float4*>(Sr + base);
                    const float4 I = *reinterpret_cast<const float4*>(Si + base);
                    num[0] = fmaf(R.x, A[a][0], fmaf(-I.x, B[a][0], num[0]));
                    num[1] = fmaf(R.y, A[a][1], fmaf(-I.y, B[a][1], num[1]));
                    num[2] = fmaf(R.z, A[a][2], fmaf(-I.z, B[a][2], num[2]));
                    num[3] = fmaf(R.w, A[a][3], fmaf(-I.w, B[a][3], num[3]));
                    den[0] += W[a][0];
                    den[1] += W[a][1];
                    den[2] += W[a][2];
                    den[3] += W[a][3];
                }
            }
            float4 o;
            o.x = num[0] / fmaxf(den[0], 1e-8f);
            o.y = num[1] / fmaxf(den[1], 1e-8f);
            o.z = num[2] / fmaxf(den[2], 1e-8f);
            o.w = num[3] / fmaxf(den[3], 1e-8f);
            *reinterpret_cast<float4*>(out + t0) = o;
        }
    }
}

extern "C" void kernel_launch(void* const* d_in, const int* in_sizes, int n_in,
                              void* d_out, int out_size, void* d_ws, size_t ws_size,
                              hipStream_t stream) {
    const float* Sr = (const float*)d_in[0];
    const float* Si = (const float*)d_in[1];
    float* out = (float*)d_out;
    (void)in_sizes; (void)n_in; (void)out_size; (void)d_ws; (void)ws_size;

    dim3 block(256);
    dim3 grid(NBLK);   // each block handles chunks b and b+1025 (same m0 -> shared trig)
    istft_ola_kernel<<<grid, block, 0, stream>>>(Sr, Si, out);
}